// Round 3
// baseline (683.993 us; speedup 1.0000x reference)
//
#include <hip/hip_runtime.h>
#include <hip/hip_bf16.h>
#include <math.h>

#define B_TOTAL 8192
#define NN      82
#define HH      10
#define OUTC    5
#define TSTEP   3
#define NB      3            // batches per block
#define THREADS 256
#define KP      96           // padded K (j) dim: 3 x 32
#define RS      10           // Xt row stride per batch (packed: overlap trick, no MP=16 pad)
#define NROWS   36           // rows needed: batch2 A-reads span rows 20..35
#define XS      104          // Xt row stride in bf16 (208 B: 16B-aligned, bank-spread)
#define UTSF    246          // uT col count/stride in floats (= NB*NN; 984B row -> quad offsets spread banks)

// LDS layout (bytes from smem base). Xt and uT ALIAS (disjoint lifetimes,
// enforced by the 4-barrier phase structure):
//   [0      .. 7488)   XtH  bf16[36][104]        \ alias
//   [7488   .. 14976)  XtL  bf16[36][104]        |  region
//   [0      .. 19680)  uT   float[20][246]       /  (19,680 B)
//   [19680  .. 23520)  wS   float[960]           (weights, NOT aliased)
#define XTL_OFF 7488
#define WS_OFF  19680
#define SMEM_BYTES 23520     // -> 23.5 KB/block -> 6 blocks/CU (was 39.9 KB -> 4)

// wS offsets (floats)
#define W3W 0
#define W4W 200
#define W5W 400
#define W3U 600
#define W5U 700
#define WOUT 800
#define B3W 900
#define B4W 910
#define B5W 920
#define B3U 930
#define B5U 940
#define BOUT 950

typedef __bf16 bf16x8 __attribute__((ext_vector_type(8)));
typedef float  f32x4  __attribute__((ext_vector_type(4)));
typedef float  f32x2  __attribute__((ext_vector_type(2)));

__device__ __forceinline__ float sigmoid_(float x) {
    return 1.0f / (1.0f + __expf(-x));
}
__device__ __forceinline__ float tanh_(float x) {
    float e = __expf(2.0f * x);
    return 1.0f - 2.0f / (e + 1.0f);
}
__device__ __forceinline__ f32x2 ld2(const float* p) {       // 8B-aligned pair (LDS)
    return *reinterpret_cast<const f32x2*>(p);
}
__device__ __forceinline__ f32x2 fma2(f32x2 a, f32x2 b, f32x2 c) {
    return __builtin_elementwise_fma(a, b, c);               // -> v_pk_fma_f32
}

// adjP layout (bf16, each 96x96 zero-padded):
//   [0]: in_adj hi   [1]: out_adj hi   [2]: in_adj lo   [3]: out_adj lo
__global__ void prep_adj_kernel(const float* __restrict__ in_adj,
                                const float* __restrict__ out_adj,
                                __hip_bfloat16* __restrict__ adjP) {
    int idx = blockIdx.x * blockDim.x + threadIdx.x;
    if (idx < 2 * KP * KP) {
        int a   = idx / (KP * KP);
        int rem = idx - a * (KP * KP);
        int i = rem / KP;
        int j = rem - i * KP;
        float v = 0.0f;
        if (i < NN && j < NN) v = (a == 0) ? in_adj[i * NN + j] : out_adj[i * NN + j];
        __hip_bfloat16 hi = __float2bfloat16(v);
        __hip_bfloat16 lo = __float2bfloat16(v - __bfloat162float(hi));
        adjP[idx]               = hi;
        adjP[2 * KP * KP + idx] = lo;
    }
}

// 6 blocks/CU (LDS: 23.5 KB). Kernel is latency-bound and scales ~linearly
// with resident blocks (measured: 150us @4 blk, 190us @3 blk). launch_bounds
// (256,6): reg cap 2048/6 = 341/wave - far above the ~180-reg live set.
extern "C" __global__ __launch_bounds__(THREADS, 6)
void ggnn_kernel(const float* __restrict__ x,
                 const __hip_bfloat16* __restrict__ adjP,
                 const float* __restrict__ w3w, const float* __restrict__ b3w,
                 const float* __restrict__ w3u, const float* __restrict__ b3u,
                 const float* __restrict__ w4w, const float* __restrict__ b4w,
                 const float* __restrict__ w5w, const float* __restrict__ b5w,
                 const float* __restrict__ w5u, const float* __restrict__ b5u,
                 const float* __restrict__ wout, const float* __restrict__ bout,
                 float* __restrict__ out0, float* __restrict__ out_fn)
{
    __shared__ __align__(16) unsigned char smem[SMEM_BYTES];
    __hip_bfloat16* XtH = reinterpret_cast<__hip_bfloat16*>(smem);
    __hip_bfloat16* XtL = reinterpret_cast<__hip_bfloat16*>(smem + XTL_OFF);
    float* uT = reinterpret_cast<float*>(smem);          // rows 0..9 = in, 10..19 = out
    float* wS = reinterpret_cast<float*>(smem + WS_OFF);

    const int t     = threadIdx.x;
    const int bbase = blockIdx.x * NB;
    const int bl    = t / NN;            // 0..2 GRU-active, 3 = spare lanes
    const int node  = t - bl * NN;
    const bool act  = (bl < NB) && (bbase + bl < B_TOTAL);
    const int b     = bbase + bl;

    const int lane = t & 63;
    const int w    = t >> 6;             // wave id 0..3
    const int lo16 = lane & 15;
    const int quad = lane >> 4;

    // ---- stage weights into LDS (coalesced; once per block) ----
    for (int i = t; i < 200; i += THREADS) {
        wS[W3W + i] = w3w[i];
        wS[W4W + i] = w4w[i];
        wS[W5W + i] = w5w[i];
    }
    if (t < 100) {
        wS[W3U + t]  = w3u[t];
        wS[W5U + t]  = w5u[t];
        wS[WOUT + t] = wout[t];
    }
    if (t < 10) {
        wS[B3W + t] = b3w[t];
        wS[B4W + t] = b4w[t];
        wS[B5W + t] = b5w[t];
        wS[B3U + t] = b3u[t];
        wS[B5U + t] = b5u[t];
    }
    if (t < OUTC) wS[BOUT + t] = bout[t];

    // ---- preload this wave's 3 (ntile,adj) B-combos into registers (step-invariant) ----
    bf16x8 Bh[3][3], Bl[3][3];           // 72 regs (VGPR/AGPR)
    int ntile_c[3], adj_c[3];
    #pragma unroll
    for (int c = 0; c < 3; ++c) {
        int co = w * 3 + c;
        int nt = co >> 1;
        int ad = co & 1;
        ntile_c[c] = nt;
        adj_c[c]   = ad;
        const __hip_bfloat16* BpH = adjP + ((size_t)ad * KP * KP
                                            + (size_t)(nt * 16 + lo16) * KP
                                            + quad * 8);
        #pragma unroll
        for (int k = 0; k < 3; ++k) {
            Bh[c][k] = *reinterpret_cast<const bf16x8*>(BpH + k * 32);
            Bl[c][k] = *reinterpret_cast<const bf16x8*>(BpH + 2 * KP * KP + k * 32);
        }
    }

    // ---- initial fill of XtH/XtL from x (coalesced read); rows = b_l*10 + h ----
    // Rows 30..35 stay garbage: A rows 10..15 only feed C rows 10..15, discarded.
    for (int idx = t; idx < NB * NN * HH; idx += THREADS) {
        int b_l = idx / (NN * HH);
        int rem = idx - b_l * (NN * HH);
        int j   = rem / HH;
        int h   = rem - j * HH;
        size_t g = (size_t)bbase * NN * HH + idx;
        float v = (g < (size_t)B_TOTAL * NN * HH) ? x[g] : 0.0f;
        __hip_bfloat16 hi = __float2bfloat16(v);
        __hip_bfloat16 lo = __float2bfloat16(v - __bfloat162float(hi));
        XtH[(b_l * RS + h) * XS + j] = hi;
        XtL[(b_l * RS + h) * XS + j] = lo;
    }
    // zero K-pad columns (j = 82..95) of DATA rows 0..29: garbage*B_pad(=0) = NaN otherwise
    {
        __hip_bfloat16 z = __float2bfloat16(0.0f);
        for (int idx = t; idx < 2 * 30 * (KP - NN); idx += THREADS) {
            int a   = idx / (30 * (KP - NN));
            int rem = idx - a * (30 * (KP - NN));
            int r   = rem / (KP - NN);
            int c   = rem - r * (KP - NN);
            (a ? XtL : XtH)[r * XS + NN + c] = z;
        }
    }

    // ---- per-thread GRU state fn (as f32x2 pairs) from x ----
    f32x2 fn2[5];
    if (act) {
        const float* xr = x + ((size_t)b * NN + node) * HH;
        #pragma unroll
        for (int p = 0; p < 5; ++p) {
            float2 v = reinterpret_cast<const float2*>(xr)[p];
            fn2[p].x = v.x; fn2[p].y = v.y;
        }
    }

    #pragma unroll 1
    for (int step = 0; step < TSTEP; ++step) {
        __syncthreads();   // [A] Xt (and at step 0: wS) fully written

        // ---- AGG: all A-reads + MFMAs first (accs for ALL mtiles held in regs),
        //      C-writes deferred past barrier [B] because uT aliases Xt. ----
        f32x4 acc[NB][3];
        #pragma unroll
        for (int mtile = 0; mtile < NB; ++mtile) {
            #pragma unroll
            for (int c = 0; c < 3; ++c) acc[mtile][c] = (f32x4){0, 0, 0, 0};
            #pragma unroll
            for (int k = 0; k < 3; ++k) {
                bf16x8 ah = *reinterpret_cast<const bf16x8*>(&XtH[(mtile * RS + lo16) * XS + quad * 8 + k * 32]);
                bf16x8 al = *reinterpret_cast<const bf16x8*>(&XtL[(mtile * RS + lo16) * XS + quad * 8 + k * 32]);
                #pragma unroll
                for (int c = 0; c < 3; ++c) {
                    acc[mtile][c] = __builtin_amdgcn_mfma_f32_16x16x32_bf16(ah, Bh[c][k], acc[mtile][c], 0, 0, 0);
                    acc[mtile][c] = __builtin_amdgcn_mfma_f32_16x16x32_bf16(al, Bh[c][k], acc[mtile][c], 0, 0, 0);
                    acc[mtile][c] = __builtin_amdgcn_mfma_f32_16x16x32_bf16(ah, Bl[c][k], acc[mtile][c], 0, 0, 0);
                }
            }
        }

        __syncthreads();   // [B] all waves done READING Xt -> safe to overwrite with uT

        // C element (reg r): row h = quad*4+r, col i = ntile*16+lo16 (valid h<10, i<82)
        #pragma unroll
        for (int mtile = 0; mtile < NB; ++mtile) {
            #pragma unroll
            for (int c = 0; c < 3; ++c) {
                int i = ntile_c[c] * 16 + lo16;
                if (i < NN) {
                    int col = mtile * NN + i;
                    float* plane0 = uT + (adj_c[c] ? 10 * UTSF : 0);
                    if (quad < 2) {
                        #pragma unroll
                        for (int r = 0; r < 4; ++r)
                            plane0[(quad * 4 + r) * UTSF + col] = acc[mtile][c][r];
                    } else if (quad == 2) {
                        plane0[8 * UTSF + col] = acc[mtile][c][0];
                        plane0[9 * UTSF + col] = acc[mtile][c][1];
                    }
                }
            }
        }

        __syncthreads();   // [C] uT fully written

        // ---- GRU: read av into regs, then fence before overwriting region with Xt ----
        f32x2 av2[10];
        if (act) {
            #pragma unroll
            for (int p = 0; p < 5; ++p) {
                av2[p].x     = uT[(2 * p) * UTSF + t];
                av2[p].y     = uT[(2 * p + 1) * UTSF + t];
                av2[5 + p].x = uT[(10 + 2 * p) * UTSF + t];
                av2[5 + p].y = uT[(10 + 2 * p + 1) * UTSF + t];
            }
        }

        __syncthreads();   // [D] all threads done READING uT -> safe to overwrite with Xt

        if (act) {
            // u3[h] = b3u[h] + w3u[h,:].fn   (shared by zv and rv — reference bug)
            float u3[HH];
            #pragma unroll
            for (int h = 0; h < HH; ++h) {
                f32x2 s2 = {0.0f, 0.0f};
                #pragma unroll
                for (int p = 0; p < 5; ++p)
                    s2 = fma2(ld2(&wS[W3U + h * HH + 2 * p]), fn2[p], s2);
                u3[h] = wS[B3U + h] + s2.x + s2.y;
            }

            float zv[HH];
            f32x2 rf2[5];
            #pragma unroll
            for (int h = 0; h < HH; ++h) {
                f32x2 z2 = {0.0f, 0.0f}, r2 = {0.0f, 0.0f};
                #pragma unroll
                for (int p = 0; p < 10; ++p) {
                    z2 = fma2(ld2(&wS[W3W + h * 20 + 2 * p]), av2[p], z2);
                    r2 = fma2(ld2(&wS[W4W + h * 20 + 2 * p]), av2[p], r2);
                }
                zv[h] = sigmoid_(wS[B3W + h] + z2.x + z2.y + u3[h]);
                float rv = sigmoid_(wS[B4W + h] + r2.x + r2.y + u3[h]);
                float fnh = (h & 1) ? fn2[h >> 1].y : fn2[h >> 1].x;
                if (h & 1) rf2[h >> 1].y = rv * fnh; else rf2[h >> 1].x = rv * fnh;
            }

            #pragma unroll
            for (int h = 0; h < HH; ++h) {
                f32x2 s2 = {0.0f, 0.0f};
                #pragma unroll
                for (int p = 0; p < 10; ++p)
                    s2 = fma2(ld2(&wS[W5W + h * 20 + 2 * p]), av2[p], s2);
                #pragma unroll
                for (int p = 0; p < 5; ++p)
                    s2 = fma2(ld2(&wS[W5U + h * HH + 2 * p]), rf2[p], s2);
                float hv = tanh_(wS[B5W + h] + wS[B5U + h] + s2.x + s2.y);
                float fnh = (h & 1) ? fn2[h >> 1].y : fn2[h >> 1].x;
                fnh = fnh + zv[h] * (hv - fnh);
                if (h & 1) fn2[h >> 1].y = fnh; else fn2[h >> 1].x = fnh;
            }

            // publish new state into Xt (hi/lo) for next step's aggregation
            if (step < TSTEP - 1) {
                #pragma unroll
                for (int h = 0; h < HH; ++h) {
                    float fnh = (h & 1) ? fn2[h >> 1].y : fn2[h >> 1].x;
                    __hip_bfloat16 hi = __float2bfloat16(fnh);
                    __hip_bfloat16 lo = __float2bfloat16(fnh - __bfloat162float(hi));
                    XtH[(bl * RS + h) * XS + node] = hi;
                    XtL[(bl * RS + h) * XS + node] = lo;
                }
            }
        }
        // re-zero K-pad columns (clobbered by uT writes) for next aggregation
        if (step < TSTEP - 1) {
            __hip_bfloat16 z = __float2bfloat16(0.0f);
            for (int idx = t; idx < 2 * 30 * (KP - NN); idx += THREADS) {
                int a   = idx / (30 * (KP - NN));
                int rem = idx - a * (30 * (KP - NN));
                int r   = rem / (KP - NN);
                int c   = rem - r * (KP - NN);
                (a ? XtL : XtH)[r * XS + NN + c] = z;
            }
        }
    }

    // ---- epilogue: out0 = tanh([fn, x] @ wout^T + bout), out_fn = fn ----
    if (act) {
        size_t row = (size_t)b * NN + node;
        const float* xr = x + row * HH;
        f32x2 xi2[5];
        #pragma unroll
        for (int p = 0; p < 5; ++p) {
            float2 v = reinterpret_cast<const float2*>(xr)[p];
            xi2[p].x = v.x; xi2[p].y = v.y;
        }

        #pragma unroll
        for (int c = 0; c < OUTC; ++c) {
            f32x2 s2 = {0.0f, 0.0f};
            #pragma unroll
            for (int p = 0; p < 5; ++p) {
                s2 = fma2(ld2(&wS[WOUT + c * 20 + 2 * p]),      fn2[p], s2);
                s2 = fma2(ld2(&wS[WOUT + c * 20 + 10 + 2 * p]), xi2[p], s2);
            }
            out0[row * OUTC + c] = tanh_(wS[BOUT + c] + s2.x + s2.y);
        }
        #pragma unroll
        for (int p = 0; p < 5; ++p) {
            reinterpret_cast<float2*>(out_fn + row * HH)[p] =
                make_float2(fn2[p].x, fn2[p].y);
        }
    }
}

extern "C" void kernel_launch(void* const* d_in, const int* in_sizes, int n_in,
                              void* d_out, int out_size, void* d_ws, size_t ws_size,
                              hipStream_t stream) {
    const float* x       = (const float*)d_in[0];
    const float* in_adj  = (const float*)d_in[1];
    const float* out_adj = (const float*)d_in[2];
    const float* w3w = (const float*)d_in[3];
    const float* b3w = (const float*)d_in[4];
    const float* w3u = (const float*)d_in[5];
    const float* b3u = (const float*)d_in[6];
    const float* w4w = (const float*)d_in[7];
    const float* b4w = (const float*)d_in[8];
    const float* w5w = (const float*)d_in[9];
    const float* b5w = (const float*)d_in[10];
    const float* w5u = (const float*)d_in[11];
    const float* b5u = (const float*)d_in[12];
    const float* wout = (const float*)d_in[13];
    const float* bout = (const float*)d_in[14];

    __hip_bfloat16* adjP = (__hip_bfloat16*)d_ws;   // 4*96*96*2 = 73.7 KB
    float* out0   = (float*)d_out;
    float* out_fn = out0 + (size_t)B_TOTAL * NN * OUTC;

    prep_adj_kernel<<<(2 * KP * KP + 255) / 256, 256, 0, stream>>>(in_adj, out_adj, adjP);

    int grid = (B_TOTAL + NB - 1) / NB;             // 2731
    ggnn_kernel<<<grid, THREADS, 0, stream>>>(
        x, adjP, w3w, b3w, w3u, b3u, w4w, b4w, w5w, b5w, w5u, b5u,
        wout, bout, out0, out_fn);
}

// Round 4
// 372.712 us; speedup vs baseline: 1.8352x; 1.8352x over previous
//
#include <hip/hip_runtime.h>
#include <hip/hip_bf16.h>
#include <math.h>

#define B_TOTAL 8192
#define NN      82
#define HH      10
#define OUTC    5
#define TSTEP   3
#define NB      3            // batches per block
#define THREADS 256
#define KP      96           // padded K (j) dim: 3 x 32
#define RS      10           // Xt row stride per batch (packed; overlap trick)
#define XS      104          // Xt row stride in bf16 (208 B: 16B-aligned, bank-spread)
#define UTSF    246          // uT col stride in floats (= NB*NN)

// LDS layout (bytes). Xt and uT ALIAS (disjoint lifetimes, 4-barrier structure):
//   [0      .. 7488)   XtH  bf16[36][104]        \ alias
//   [7488   .. 14976)  XtL  bf16[36][104]        |  region
//   [0      .. 19680)  uT   float[20][246]       /  (19,680 B)
//   [19680  .. 23520)  wS   float[960]
#define XTL_OFF 7488
#define WS_OFF  19680
#define SMEM_BYTES 23520     // 23.5 KB/block -> LDS allows 6 blocks/CU; regs set 5

// wS offsets (floats)
#define W3W 0
#define W4W 200
#define W5W 400
#define W3U 600
#define W5U 700
#define WOUT 800
#define B3W 900
#define B4W 910
#define B5W 920
#define B3U 930
#define B5U 940
#define BOUT 950

typedef __bf16 bf16x8 __attribute__((ext_vector_type(8)));
typedef float  f32x4  __attribute__((ext_vector_type(4)));
typedef float  f32x2  __attribute__((ext_vector_type(2)));

__device__ __forceinline__ float sigmoid_(float x) {
    return 1.0f / (1.0f + __expf(-x));
}
__device__ __forceinline__ float tanh_(float x) {
    float e = __expf(2.0f * x);
    return 1.0f - 2.0f / (e + 1.0f);
}
__device__ __forceinline__ f32x2 ld2(const float* p) {       // 8B-aligned pair (LDS)
    return *reinterpret_cast<const f32x2*>(p);
}
__device__ __forceinline__ f32x2 fma2(f32x2 a, f32x2 b, f32x2 c) {
    return __builtin_elementwise_fma(a, b, c);               // -> v_pk_fma_f32
}

// adjP layout (bf16, each 96x96 zero-padded):
//   [0]: in_adj hi   [1]: out_adj hi   [2]: in_adj lo   [3]: out_adj lo
__global__ void prep_adj_kernel(const float* __restrict__ in_adj,
                                const float* __restrict__ out_adj,
                                __hip_bfloat16* __restrict__ adjP) {
    int idx = blockIdx.x * blockDim.x + threadIdx.x;
    if (idx < 2 * KP * KP) {
        int a   = idx / (KP * KP);
        int rem = idx - a * (KP * KP);
        int i = rem / KP;
        int j = rem - i * KP;
        float v = 0.0f;
        if (i < NN && j < NN) v = (a == 0) ? in_adj[i * NN + j] : out_adj[i * NN + j];
        __hip_bfloat16 hi = __float2bfloat16(v);
        __hip_bfloat16 lo = __float2bfloat16(v - __bfloat162float(hi));
        adjP[idx]               = hi;
        adjP[2 * KP * KP + idx] = lo;
    }
}

// launch_bounds(256,5): arch-VGPR cap 256/5 = 51 (measured rule: cap = 256/waves),
// unified V+A budget 512/5 = 102. B-fragments now STREAMED from L2 per step
// (not held: that was 72 persistent regs; at (256,6)'s 85-reg budget everything
// spilled to scratch -> 2 GB HBM traffic, 615 us). 5 blocks/CU target.
extern "C" __global__ __launch_bounds__(THREADS, 5)
void ggnn_kernel(const float* __restrict__ x,
                 const __hip_bfloat16* __restrict__ adjP,
                 const float* __restrict__ w3w, const float* __restrict__ b3w,
                 const float* __restrict__ w3u, const float* __restrict__ b3u,
                 const float* __restrict__ w4w, const float* __restrict__ b4w,
                 const float* __restrict__ w5w, const float* __restrict__ b5w,
                 const float* __restrict__ w5u, const float* __restrict__ b5u,
                 const float* __restrict__ wout, const float* __restrict__ bout,
                 float* __restrict__ out0, float* __restrict__ out_fn)
{
    __shared__ __align__(16) unsigned char smem[SMEM_BYTES];
    __hip_bfloat16* XtH = reinterpret_cast<__hip_bfloat16*>(smem);
    __hip_bfloat16* XtL = reinterpret_cast<__hip_bfloat16*>(smem + XTL_OFF);
    float* uT = reinterpret_cast<float*>(smem);          // rows 0..9 = in, 10..19 = out
    float* wS = reinterpret_cast<float*>(smem + WS_OFF);

    const int t     = threadIdx.x;
    const int bbase = blockIdx.x * NB;
    const int bl    = t / NN;            // 0..2 GRU-active, 3 = spare lanes
    const int node  = t - bl * NN;
    const bool act  = (bl < NB) && (bbase + bl < B_TOTAL);
    const int b     = bbase + bl;

    const int lane = t & 63;
    const int w    = t >> 6;             // wave id 0..3
    const int lo16 = lane & 15;
    const int quad = lane >> 4;

    // ---- stage weights into LDS (coalesced; once per block) ----
    for (int i = t; i < 200; i += THREADS) {
        wS[W3W + i] = w3w[i];
        wS[W4W + i] = w4w[i];
        wS[W5W + i] = w5w[i];
    }
    if (t < 100) {
        wS[W3U + t]  = w3u[t];
        wS[W5U + t]  = w5u[t];
        wS[WOUT + t] = wout[t];
    }
    if (t < 10) {
        wS[B3W + t] = b3w[t];
        wS[B4W + t] = b4w[t];
        wS[B5W + t] = b5w[t];
        wS[B3U + t] = b3u[t];
        wS[B5U + t] = b5u[t];
    }
    if (t < OUTC) wS[BOUT + t] = bout[t];

    // ---- per-wave (ntile,adj) combo mapping + step-invariant B base pointers ----
    int ntile_c[3], adj_c[3];
    const __hip_bfloat16* Bbase[3];
    #pragma unroll
    for (int c = 0; c < 3; ++c) {
        int co = w * 3 + c;
        int nt = co >> 1;
        int ad = co & 1;
        ntile_c[c] = nt;
        adj_c[c]   = ad;
        Bbase[c] = adjP + ((size_t)ad * KP * KP + (size_t)(nt * 16 + lo16) * KP + quad * 8);
    }

    // ---- initial fill of XtH/XtL from x (coalesced read); rows = b_l*10 + h ----
    // Rows 30..35 stay garbage: A rows 10..15 only feed C rows 10..15, discarded.
    for (int idx = t; idx < NB * NN * HH; idx += THREADS) {
        int b_l = idx / (NN * HH);
        int rem = idx - b_l * (NN * HH);
        int j   = rem / HH;
        int h   = rem - j * HH;
        size_t g = (size_t)bbase * NN * HH + idx;
        float v = (g < (size_t)B_TOTAL * NN * HH) ? x[g] : 0.0f;
        __hip_bfloat16 hi = __float2bfloat16(v);
        __hip_bfloat16 lo = __float2bfloat16(v - __bfloat162float(hi));
        XtH[(b_l * RS + h) * XS + j] = hi;
        XtL[(b_l * RS + h) * XS + j] = lo;
    }
    // zero K-pad columns (j = 82..95) of data rows 0..29
    {
        __hip_bfloat16 z = __float2bfloat16(0.0f);
        for (int idx = t; idx < 2 * 30 * (KP - NN); idx += THREADS) {
            int a   = idx / (30 * (KP - NN));
            int rem = idx - a * (30 * (KP - NN));
            int r   = rem / (KP - NN);
            int c   = rem - r * (KP - NN);
            (a ? XtL : XtH)[r * XS + NN + c] = z;
        }
    }

    // ---- per-thread GRU state fn (as f32x2 pairs) from x ----
    f32x2 fn2[5];
    if (act) {
        const float* xr = x + ((size_t)b * NN + node) * HH;
        #pragma unroll
        for (int p = 0; p < 5; ++p) {
            float2 v = reinterpret_cast<const float2*>(xr)[p];
            fn2[p].x = v.x; fn2[p].y = v.y;
        }
    }

    #pragma unroll 1
    for (int step = 0; step < TSTEP; ++step) {
        __syncthreads();   // [A] Xt (and at step 0: wS) fully written

        // ---- AGG: A from LDS, B streamed from L2 (reused across 3 mtiles).
        //      All accs held (deferred C-write past [B]: uT aliases Xt). ----
        f32x4 acc[NB][3];
        #pragma unroll
        for (int m = 0; m < NB; ++m)
            #pragma unroll
            for (int c = 0; c < 3; ++c) acc[m][c] = (f32x4){0, 0, 0, 0};

        #pragma unroll
        for (int k = 0; k < 3; ++k) {
            bf16x8 ah[NB], al[NB];
            #pragma unroll
            for (int m = 0; m < NB; ++m) {
                ah[m] = *reinterpret_cast<const bf16x8*>(&XtH[(m * RS + lo16) * XS + quad * 8 + k * 32]);
                al[m] = *reinterpret_cast<const bf16x8*>(&XtL[(m * RS + lo16) * XS + quad * 8 + k * 32]);
            }
            #pragma unroll
            for (int c = 0; c < 3; ++c) {
                bf16x8 bh = *reinterpret_cast<const bf16x8*>(Bbase[c] + k * 32);
                bf16x8 bl_ = *reinterpret_cast<const bf16x8*>(Bbase[c] + 2 * KP * KP + k * 32);
                #pragma unroll
                for (int m = 0; m < NB; ++m) {
                    acc[m][c] = __builtin_amdgcn_mfma_f32_16x16x32_bf16(ah[m], bh,  acc[m][c], 0, 0, 0);
                    acc[m][c] = __builtin_amdgcn_mfma_f32_16x16x32_bf16(al[m], bh,  acc[m][c], 0, 0, 0);
                    acc[m][c] = __builtin_amdgcn_mfma_f32_16x16x32_bf16(ah[m], bl_, acc[m][c], 0, 0, 0);
                }
            }
        }

        __syncthreads();   // [B] all waves done READING Xt -> safe to overwrite with uT

        // C element (reg r): row h = quad*4+r, col i = ntile*16+lo16 (valid h<10, i<82)
        #pragma unroll
        for (int m = 0; m < NB; ++m) {
            #pragma unroll
            for (int c = 0; c < 3; ++c) {
                int i = ntile_c[c] * 16 + lo16;
                if (i < NN) {
                    int col = m * NN + i;
                    float* plane0 = uT + (adj_c[c] ? 10 * UTSF : 0);
                    if (quad < 2) {
                        #pragma unroll
                        for (int r = 0; r < 4; ++r)
                            plane0[(quad * 4 + r) * UTSF + col] = acc[m][c][r];
                    } else if (quad == 2) {
                        plane0[8 * UTSF + col] = acc[m][c][0];
                        plane0[9 * UTSF + col] = acc[m][c][1];
                    }
                }
            }
        }

        __syncthreads();   // [C] uT fully written

        // ---- GRU: read av into regs, fence, then compute + republish Xt ----
        f32x2 av2[10];
        if (act) {
            #pragma unroll
            for (int p = 0; p < 5; ++p) {
                av2[p].x     = uT[(2 * p) * UTSF + t];
                av2[p].y     = uT[(2 * p + 1) * UTSF + t];
                av2[5 + p].x = uT[(10 + 2 * p) * UTSF + t];
                av2[5 + p].y = uT[(10 + 2 * p + 1) * UTSF + t];
            }
        }

        __syncthreads();   // [D] all threads done READING uT -> safe to overwrite with Xt

        if (act) {
            float zv[HH];
            f32x2 rf2[5];
            #pragma unroll
            for (int h = 0; h < HH; ++h) {
                // u3h inlined (shared by zv and rv — reference bug reusing w3u)
                f32x2 su = {0.0f, 0.0f};
                #pragma unroll
                for (int p = 0; p < 5; ++p)
                    su = fma2(ld2(&wS[W3U + h * HH + 2 * p]), fn2[p], su);
                float u3h = wS[B3U + h] + su.x + su.y;

                f32x2 z2 = {0.0f, 0.0f}, r2 = {0.0f, 0.0f};
                #pragma unroll
                for (int p = 0; p < 10; ++p) {
                    z2 = fma2(ld2(&wS[W3W + h * 20 + 2 * p]), av2[p], z2);
                    r2 = fma2(ld2(&wS[W4W + h * 20 + 2 * p]), av2[p], r2);
                }
                zv[h] = sigmoid_(wS[B3W + h] + z2.x + z2.y + u3h);
                float rv = sigmoid_(wS[B4W + h] + r2.x + r2.y + u3h);
                float fnh = (h & 1) ? fn2[h >> 1].y : fn2[h >> 1].x;
                if (h & 1) rf2[h >> 1].y = rv * fnh; else rf2[h >> 1].x = rv * fnh;
            }

            #pragma unroll
            for (int h = 0; h < HH; ++h) {
                f32x2 s2 = {0.0f, 0.0f};
                #pragma unroll
                for (int p = 0; p < 10; ++p)
                    s2 = fma2(ld2(&wS[W5W + h * 20 + 2 * p]), av2[p], s2);
                #pragma unroll
                for (int p = 0; p < 5; ++p)
                    s2 = fma2(ld2(&wS[W5U + h * HH + 2 * p]), rf2[p], s2);
                float hv = tanh_(wS[B5W + h] + wS[B5U + h] + s2.x + s2.y);
                float fnh = (h & 1) ? fn2[h >> 1].y : fn2[h >> 1].x;
                fnh = fnh + zv[h] * (hv - fnh);
                if (h & 1) fn2[h >> 1].y = fnh; else fn2[h >> 1].x = fnh;
            }

            // publish new state into Xt (hi/lo) for next step's aggregation
            if (step < TSTEP - 1) {
                #pragma unroll
                for (int h = 0; h < HH; ++h) {
                    float fnh = (h & 1) ? fn2[h >> 1].y : fn2[h >> 1].x;
                    __hip_bfloat16 hi = __float2bfloat16(fnh);
                    __hip_bfloat16 lo = __float2bfloat16(fnh - __bfloat162float(hi));
                    XtH[(bl * RS + h) * XS + node] = hi;
                    XtL[(bl * RS + h) * XS + node] = lo;
                }
            }
        }
        // re-zero K-pad columns (clobbered by uT writes) for next aggregation
        if (step < TSTEP - 1) {
            __hip_bfloat16 z = __float2bfloat16(0.0f);
            for (int idx = t; idx < 2 * 30 * (KP - NN); idx += THREADS) {
                int a   = idx / (30 * (KP - NN));
                int rem = idx - a * (30 * (KP - NN));
                int r   = rem / (KP - NN);
                int c   = rem - r * (KP - NN);
                (a ? XtL : XtH)[r * XS + NN + c] = z;
            }
        }
    }

    // ---- epilogue: out0 = tanh([fn, x] @ wout^T + bout), out_fn = fn ----
    if (act) {
        size_t row = (size_t)b * NN + node;
        const float* xr = x + row * HH;
        f32x2 xi2[5];
        #pragma unroll
        for (int p = 0; p < 5; ++p) {
            float2 v = reinterpret_cast<const float2*>(xr)[p];
            xi2[p].x = v.x; xi2[p].y = v.y;
        }

        #pragma unroll
        for (int c = 0; c < OUTC; ++c) {
            f32x2 s2 = {0.0f, 0.0f};
            #pragma unroll
            for (int p = 0; p < 5; ++p) {
                s2 = fma2(ld2(&wS[WOUT + c * 20 + 2 * p]),      fn2[p], s2);
                s2 = fma2(ld2(&wS[WOUT + c * 20 + 10 + 2 * p]), xi2[p], s2);
            }
            out0[row * OUTC + c] = tanh_(wS[BOUT + c] + s2.x + s2.y);
        }
        #pragma unroll
        for (int p = 0; p < 5; ++p) {
            reinterpret_cast<float2*>(out_fn + row * HH)[p] =
                make_float2(fn2[p].x, fn2[p].y);
        }
    }
}

extern "C" void kernel_launch(void* const* d_in, const int* in_sizes, int n_in,
                              void* d_out, int out_size, void* d_ws, size_t ws_size,
                              hipStream_t stream) {
    const float* x       = (const float*)d_in[0];
    const float* in_adj  = (const float*)d_in[1];
    const float* out_adj = (const float*)d_in[2];
    const float* w3w = (const float*)d_in[3];
    const float* b3w = (const float*)d_in[4];
    const float* w3u = (const float*)d_in[5];
    const float* b3u = (const float*)d_in[6];
    const float* w4w = (const float*)d_in[7];
    const float* b4w = (const float*)d_in[8];
    const float* w5w = (const float*)d_in[9];
    const float* b5w = (const float*)d_in[10];
    const float* w5u = (const float*)d_in[11];
    const float* b5u = (const float*)d_in[12];
    const float* wout = (const float*)d_in[13];
    const float* bout = (const float*)d_in[14];

    __hip_bfloat16* adjP = (__hip_bfloat16*)d_ws;   // 4*96*96*2 = 73.7 KB
    float* out0   = (float*)d_out;
    float* out_fn = out0 + (size_t)B_TOTAL * NN * OUTC;

    prep_adj_kernel<<<(2 * KP * KP + 255) / 256, 256, 0, stream>>>(in_adj, out_adj, adjP);

    int grid = (B_TOTAL + NB - 1) / NB;             // 2731
    ggnn_kernel<<<grid, THREADS, 0, stream>>>(
        x, adjP, w3w, b3w, w3u, b3u, w4w, b4w, w5w, b5w, w5u, b5u,
        wout, bout, out0, out_fn);
}

// Round 5
// 254.226 us; speedup vs baseline: 2.6905x; 1.4661x over previous
//
#include <hip/hip_runtime.h>
#include <hip/hip_bf16.h>
#include <math.h>

#define B_TOTAL 8192
#define NN      82
#define HH      10
#define OUTC    5
#define TSTEP   3
#define NB      2            // batches per block (cut from 3: -12 acc regs, fits 5-blk budget)
#define THREADS 256
#define KP      96           // padded K (j) dim: 3 x 32
#define RS      10           // Xt row stride per batch (packed; overlap trick)
#define NROWS   26           // batch1 A-reads span rows 10..25
#define XS      104          // Xt row stride in bf16 (208 B: 16B-aligned, bank-spread)
#define UTSF    164          // uT col stride in floats (= NB*NN)

// LDS layout (bytes). Xt and uT ALIAS (disjoint lifetimes, 4-barrier structure):
//   [0      .. 5408)   XtH  bf16[26][104]        \ alias
//   [5408   .. 10816)  XtL  bf16[26][104]        |  region
//   [0      .. 13120)  uT   float[20][164]       /  (13,120 B)
//   [13120  .. 16960)  wS   float[960]
#define XTL_OFF 5408
#define WS_OFF  13120
#define SMEM_BYTES 16960     // 16.9 KB/block: LDS would allow 9 blocks; regs set 5

// wS offsets (floats)
#define W3W 0
#define W4W 200
#define W5W 400
#define W3U 600
#define W5U 700
#define WOUT 800
#define B3W 900
#define B4W 910
#define B5W 920
#define B3U 930
#define B5U 940
#define BOUT 950

typedef __bf16 bf16x8 __attribute__((ext_vector_type(8)));
typedef float  f32x4  __attribute__((ext_vector_type(4)));
typedef float  f32x2  __attribute__((ext_vector_type(2)));

__device__ __forceinline__ float sigmoid_(float x) {
    return 1.0f / (1.0f + __expf(-x));
}
__device__ __forceinline__ float tanh_(float x) {
    float e = __expf(2.0f * x);
    return 1.0f - 2.0f / (e + 1.0f);
}
__device__ __forceinline__ f32x2 ld2(const float* p) {       // 8B-aligned pair (LDS)
    return *reinterpret_cast<const f32x2*>(p);
}
__device__ __forceinline__ f32x2 fma2(f32x2 a, f32x2 b, f32x2 c) {
    return __builtin_elementwise_fma(a, b, c);               // -> v_pk_fma_f32
}

// adjP layout (bf16, each 96x96 zero-padded):
//   [0]: in_adj hi   [1]: out_adj hi   [2]: in_adj lo   [3]: out_adj lo
__global__ void prep_adj_kernel(const float* __restrict__ in_adj,
                                const float* __restrict__ out_adj,
                                __hip_bfloat16* __restrict__ adjP) {
    int idx = blockIdx.x * blockDim.x + threadIdx.x;
    if (idx < 2 * KP * KP) {
        int a   = idx / (KP * KP);
        int rem = idx - a * (KP * KP);
        int i = rem / KP;
        int j = rem - i * KP;
        float v = 0.0f;
        if (i < NN && j < NN) v = (a == 0) ? in_adj[i * NN + j] : out_adj[i * NN + j];
        __hip_bfloat16 hi = __float2bfloat16(v);
        __hip_bfloat16 lo = __float2bfloat16(v - __bfloat162float(hi));
        adjP[idx]               = hi;
        adjP[2 * KP * KP + idx] = lo;
    }
}

// launch_bounds(256,5): budget ~48 arch VGPR + ~48 AGPR (measured rule:
// arch cap = 256/waves). Demand cut vs r4: NB=2 -> 6 acc tiles/wave (24 regs,
// AGPR-able), k-loop rolled so only one (ah,al,B) set is in flight at a time.
// Est. peak ~81 unified << 96 budget. 5 blocks/CU target (dur ~ 600/blocks law).
extern "C" __global__ __launch_bounds__(THREADS, 5)
void ggnn_kernel(const float* __restrict__ x,
                 const __hip_bfloat16* __restrict__ adjP,
                 const float* __restrict__ w3w, const float* __restrict__ b3w,
                 const float* __restrict__ w3u, const float* __restrict__ b3u,
                 const float* __restrict__ w4w, const float* __restrict__ b4w,
                 const float* __restrict__ w5w, const float* __restrict__ b5w,
                 const float* __restrict__ w5u, const float* __restrict__ b5u,
                 const float* __restrict__ wout, const float* __restrict__ bout,
                 float* __restrict__ out0, float* __restrict__ out_fn)
{
    __shared__ __align__(16) unsigned char smem[SMEM_BYTES];
    __hip_bfloat16* XtH = reinterpret_cast<__hip_bfloat16*>(smem);
    __hip_bfloat16* XtL = reinterpret_cast<__hip_bfloat16*>(smem + XTL_OFF);
    float* uT = reinterpret_cast<float*>(smem);          // rows 0..9 = in, 10..19 = out
    float* wS = reinterpret_cast<float*>(smem + WS_OFF);

    const int t     = threadIdx.x;
    const int bbase = blockIdx.x * NB;
    const int bl    = t / NN;            // 0..1 GRU-active, 2..3 = spare lanes
    const int node  = t - bl * NN;
    const bool act  = (bl < NB) && (bbase + bl < B_TOTAL);
    const int b     = bbase + bl;

    const int lane = t & 63;
    const int w    = t >> 6;             // wave id 0..3
    const int lo16 = lane & 15;
    const int quad = lane >> 4;

    // ---- stage weights into LDS (coalesced; once per block) ----
    for (int i = t; i < 200; i += THREADS) {
        wS[W3W + i] = w3w[i];
        wS[W4W + i] = w4w[i];
        wS[W5W + i] = w5w[i];
    }
    if (t < 100) {
        wS[W3U + t]  = w3u[t];
        wS[W5U + t]  = w5u[t];
        wS[WOUT + t] = wout[t];
    }
    if (t < 10) {
        wS[B3W + t] = b3w[t];
        wS[B4W + t] = b4w[t];
        wS[B5W + t] = b5w[t];
        wS[B3U + t] = b3u[t];
        wS[B5U + t] = b5u[t];
    }
    if (t < OUTC) wS[BOUT + t] = bout[t];

    // ---- per-wave (ntile,adj) combo mapping: B streamed from L2 each use ----
    int ntile_c[3], adj_c[3], Boff[3];
    #pragma unroll
    for (int c = 0; c < 3; ++c) {
        int co = w * 3 + c;
        int nt = co >> 1;
        int ad = co & 1;
        ntile_c[c] = nt;
        adj_c[c]   = ad;
        Boff[c] = ad * KP * KP + (nt * 16 + lo16) * KP + quad * 8;
    }

    // ---- initial fill of XtH/XtL from x (coalesced read); rows = b_l*10 + h ----
    // Rows 20..25 stay garbage: A rows 10..15 feed only C rows 10..15, discarded.
    for (int idx = t; idx < NB * NN * HH; idx += THREADS) {
        int b_l = idx / (NN * HH);
        int rem = idx - b_l * (NN * HH);
        int j   = rem / HH;
        int h   = rem - j * HH;
        size_t g = (size_t)bbase * NN * HH + idx;
        float v = (g < (size_t)B_TOTAL * NN * HH) ? x[g] : 0.0f;
        __hip_bfloat16 hi = __float2bfloat16(v);
        __hip_bfloat16 lo = __float2bfloat16(v - __bfloat162float(hi));
        XtH[(b_l * RS + h) * XS + j] = hi;
        XtL[(b_l * RS + h) * XS + j] = lo;
    }
    // zero K-pad columns (j = 82..95) of data rows 0..19 (garbage there would
    // multiply B pad rows: 0*NaN = NaN in live C rows)
    {
        __hip_bfloat16 z = __float2bfloat16(0.0f);
        for (int idx = t; idx < 2 * (NB * RS) * (KP - NN); idx += THREADS) {
            int a   = idx / ((NB * RS) * (KP - NN));
            int rem = idx - a * ((NB * RS) * (KP - NN));
            int r   = rem / (KP - NN);
            int c   = rem - r * (KP - NN);
            (a ? XtL : XtH)[r * XS + NN + c] = z;
        }
    }

    // ---- per-thread GRU state fn (as f32x2 pairs) from x ----
    f32x2 fn2[5];
    if (act) {
        const float* xr = x + ((size_t)b * NN + node) * HH;
        #pragma unroll
        for (int p = 0; p < 5; ++p) {
            float2 v = reinterpret_cast<const float2*>(xr)[p];
            fn2[p].x = v.x; fn2[p].y = v.y;
        }
    }

    #pragma unroll 1
    for (int step = 0; step < TSTEP; ++step) {
        __syncthreads();   // [A] Xt (and at step 0: wS) fully written

        // ---- AGG: A from LDS, B streamed from L2. All 6 accs held across [B]
        //      (C-write deferred: uT aliases Xt). k rolled to cap in-flight regs.
        f32x4 acc[NB][3];
        #pragma unroll
        for (int m = 0; m < NB; ++m)
            #pragma unroll
            for (int c = 0; c < 3; ++c) acc[m][c] = (f32x4){0, 0, 0, 0};

        #pragma unroll 1
        for (int k = 0; k < 3; ++k) {
            bf16x8 ah[NB], al[NB];
            #pragma unroll
            for (int m = 0; m < NB; ++m) {
                ah[m] = *reinterpret_cast<const bf16x8*>(&XtH[(m * RS + lo16) * XS + quad * 8 + k * 32]);
                al[m] = *reinterpret_cast<const bf16x8*>(&XtL[(m * RS + lo16) * XS + quad * 8 + k * 32]);
            }
            #pragma unroll
            for (int c = 0; c < 3; ++c) {
                const __hip_bfloat16* bp = adjP + Boff[c] + k * 32;
                bf16x8 bh  = *reinterpret_cast<const bf16x8*>(bp);
                bf16x8 bl_ = *reinterpret_cast<const bf16x8*>(bp + 2 * KP * KP);
                #pragma unroll
                for (int m = 0; m < NB; ++m) {
                    acc[m][c] = __builtin_amdgcn_mfma_f32_16x16x32_bf16(ah[m], bh,  acc[m][c], 0, 0, 0);
                    acc[m][c] = __builtin_amdgcn_mfma_f32_16x16x32_bf16(al[m], bh,  acc[m][c], 0, 0, 0);
                    acc[m][c] = __builtin_amdgcn_mfma_f32_16x16x32_bf16(ah[m], bl_, acc[m][c], 0, 0, 0);
                }
            }
        }

        __syncthreads();   // [B] all waves done READING Xt -> safe to overwrite with uT

        // C element (reg r): row h = quad*4+r, col i = ntile*16+lo16 (valid h<10, i<82)
        #pragma unroll
        for (int m = 0; m < NB; ++m) {
            #pragma unroll
            for (int c = 0; c < 3; ++c) {
                int i = ntile_c[c] * 16 + lo16;
                if (i < NN) {
                    int col = m * NN + i;
                    float* plane0 = uT + (adj_c[c] ? 10 * UTSF : 0);
                    if (quad < 2) {
                        #pragma unroll
                        for (int r = 0; r < 4; ++r)
                            plane0[(quad * 4 + r) * UTSF + col] = acc[m][c][r];
                    } else if (quad == 2) {
                        plane0[8 * UTSF + col] = acc[m][c][0];
                        plane0[9 * UTSF + col] = acc[m][c][1];
                    }
                }
            }
        }

        __syncthreads();   // [C] uT fully written

        // ---- GRU: read av into regs, fence, then compute + republish Xt ----
        f32x2 av2[10];
        if (act) {
            #pragma unroll
            for (int p = 0; p < 5; ++p) {
                av2[p].x     = uT[(2 * p) * UTSF + t];
                av2[p].y     = uT[(2 * p + 1) * UTSF + t];
                av2[5 + p].x = uT[(10 + 2 * p) * UTSF + t];
                av2[5 + p].y = uT[(10 + 2 * p + 1) * UTSF + t];
            }
        }

        __syncthreads();   // [D] all threads done READING uT -> safe to overwrite with Xt

        if (act) {
            float zv[HH];
            f32x2 rf2[5];
            #pragma unroll
            for (int h = 0; h < HH; ++h) {
                // u3h inlined (shared by zv and rv — reference bug reusing w3u)
                f32x2 su = {0.0f, 0.0f};
                #pragma unroll
                for (int p = 0; p < 5; ++p)
                    su = fma2(ld2(&wS[W3U + h * HH + 2 * p]), fn2[p], su);
                float u3h = wS[B3U + h] + su.x + su.y;

                f32x2 z2 = {0.0f, 0.0f}, r2 = {0.0f, 0.0f};
                #pragma unroll
                for (int p = 0; p < 10; ++p) {
                    z2 = fma2(ld2(&wS[W3W + h * 20 + 2 * p]), av2[p], z2);
                    r2 = fma2(ld2(&wS[W4W + h * 20 + 2 * p]), av2[p], r2);
                }
                zv[h] = sigmoid_(wS[B3W + h] + z2.x + z2.y + u3h);
                float rv = sigmoid_(wS[B4W + h] + r2.x + r2.y + u3h);
                float fnh = (h & 1) ? fn2[h >> 1].y : fn2[h >> 1].x;
                if (h & 1) rf2[h >> 1].y = rv * fnh; else rf2[h >> 1].x = rv * fnh;
            }

            #pragma unroll
            for (int h = 0; h < HH; ++h) {
                f32x2 s2 = {0.0f, 0.0f};
                #pragma unroll
                for (int p = 0; p < 10; ++p)
                    s2 = fma2(ld2(&wS[W5W + h * 20 + 2 * p]), av2[p], s2);
                #pragma unroll
                for (int p = 0; p < 5; ++p)
                    s2 = fma2(ld2(&wS[W5U + h * HH + 2 * p]), rf2[p], s2);
                float hv = tanh_(wS[B5W + h] + wS[B5U + h] + s2.x + s2.y);
                float fnh = (h & 1) ? fn2[h >> 1].y : fn2[h >> 1].x;
                fnh = fnh + zv[h] * (hv - fnh);
                if (h & 1) fn2[h >> 1].y = fnh; else fn2[h >> 1].x = fnh;
            }

            // publish new state into Xt (hi/lo) for next step's aggregation
            if (step < TSTEP - 1) {
                #pragma unroll
                for (int h = 0; h < HH; ++h) {
                    float fnh = (h & 1) ? fn2[h >> 1].y : fn2[h >> 1].x;
                    __hip_bfloat16 hi = __float2bfloat16(fnh);
                    __hip_bfloat16 lo = __float2bfloat16(fnh - __bfloat162float(hi));
                    XtH[(bl * RS + h) * XS + node] = hi;
                    XtL[(bl * RS + h) * XS + node] = lo;
                }
            }
        }
        // re-zero K-pad columns (clobbered by uT writes) for next aggregation
        if (step < TSTEP - 1) {
            __hip_bfloat16 z = __float2bfloat16(0.0f);
            for (int idx = t; idx < 2 * (NB * RS) * (KP - NN); idx += THREADS) {
                int a   = idx / ((NB * RS) * (KP - NN));
                int rem = idx - a * ((NB * RS) * (KP - NN));
                int r   = rem / (KP - NN);
                int c   = rem - r * (KP - NN);
                (a ? XtL : XtH)[r * XS + NN + c] = z;
            }
        }
    }

    // ---- epilogue: out0 = tanh([fn, x] @ wout^T + bout), out_fn = fn ----
    if (act) {
        size_t row = (size_t)b * NN + node;
        const float* xr = x + row * HH;
        f32x2 xi2[5];
        #pragma unroll
        for (int p = 0; p < 5; ++p) {
            float2 v = reinterpret_cast<const float2*>(xr)[p];
            xi2[p].x = v.x; xi2[p].y = v.y;
        }

        #pragma unroll
        for (int c = 0; c < OUTC; ++c) {
            f32x2 s2 = {0.0f, 0.0f};
            #pragma unroll
            for (int p = 0; p < 5; ++p) {
                s2 = fma2(ld2(&wS[WOUT + c * 20 + 2 * p]),      fn2[p], s2);
                s2 = fma2(ld2(&wS[WOUT + c * 20 + 10 + 2 * p]), xi2[p], s2);
            }
            out0[row * OUTC + c] = tanh_(wS[BOUT + c] + s2.x + s2.y);
        }
        #pragma unroll
        for (int p = 0; p < 5; ++p) {
            reinterpret_cast<float2*>(out_fn + row * HH)[p] =
                make_float2(fn2[p].x, fn2[p].y);
        }
    }
}

extern "C" void kernel_launch(void* const* d_in, const int* in_sizes, int n_in,
                              void* d_out, int out_size, void* d_ws, size_t ws_size,
                              hipStream_t stream) {
    const float* x       = (const float*)d_in[0];
    const float* in_adj  = (const float*)d_in[1];
    const float* out_adj = (const float*)d_in[2];
    const float* w3w = (const float*)d_in[3];
    const float* b3w = (const float*)d_in[4];
    const float* w3u = (const float*)d_in[5];
    const float* b3u = (const float*)d_in[6];
    const float* w4w = (const float*)d_in[7];
    const float* b4w = (const float*)d_in[8];
    const float* w5w = (const float*)d_in[9];
    const float* b5w = (const float*)d_in[10];
    const float* w5u = (const float*)d_in[11];
    const float* b5u = (const float*)d_in[12];
    const float* wout = (const float*)d_in[13];
    const float* bout = (const float*)d_in[14];

    __hip_bfloat16* adjP = (__hip_bfloat16*)d_ws;   // 4*96*96*2 = 73.7 KB
    float* out0   = (float*)d_out;
    float* out_fn = out0 + (size_t)B_TOTAL * NN * OUTC;

    prep_adj_kernel<<<(2 * KP * KP + 255) / 256, 256, 0, stream>>>(in_adj, out_adj, adjP);

    int grid = (B_TOTAL + NB - 1) / NB;             // 4096
    ggnn_kernel<<<grid, THREADS, 0, stream>>>(
        x, adjP, w3w, b3w, w3u, b3u, w4w, b4w, w5w, b5w, w5u, b5u,
        wout, bout, out0, out_fn);
}